// Round 1
// baseline (393.035 us; speedup 1.0000x reference)
//
#include <hip/hip_runtime.h>
#include <cstdint>
#include <cmath>

// ---------------------------------------------------------------------------
// Tiled conv1d (stride 1, pad = (K-1)/2) acting as GEMM over (Cout x T) tiles.
// Block: 256 threads -> 64 co x 64 t tile, 4x4 register tile per thread.
// LDS: x chunk [16][XWP] (aligned for b128 reads), w chunk transposed
//      ws_t[ci*K+dk][64] so 4 consecutive co weights are one ds_read_b128.
// ---------------------------------------------------------------------------
template<int CIN, int K, bool RELU>
__global__ __launch_bounds__(256) void conv_tile(
    const float* __restrict__ x, const float* __restrict__ w,
    const float* __restrict__ bias, float* __restrict__ y,
    int Cout, int T)
{
  constexpr int CI  = 16;
  constexpr int PAD = (K == 3) ? 1 : 0;
  constexpr int XWP = (K == 3) ? 68 : 64;   // padded to 16B multiple
  const int b   = blockIdx.z;
  const int co0 = blockIdx.y * 64;
  const int t0  = blockIdx.x * 64;
  const int tid = threadIdx.x;
  const int tx  = tid & 15;   // t group: t = t0 + tx*4 + j
  const int ty  = tid >> 4;   // co group: co = co0 + ty*4 + i

  __shared__ __align__(16) float xs[CI][XWP];
  __shared__ __align__(16) float ws_t[CI * K][64];

  float acc[4][4];
  #pragma unroll
  for (int i = 0; i < 4; ++i)
    #pragma unroll
    for (int j = 0; j < 4; ++j) acc[i][j] = 0.f;

  for (int c0 = 0; c0 < CIN; c0 += CI) {
    __syncthreads();
    // stage x chunk (zero-padded at batch edges)
    for (int idx = tid; idx < CI * XWP; idx += 256) {
      int ci = idx / XWP, u = idx - ci * XWP;
      int gt = t0 + u - PAD;
      float v = 0.f;
      if (gt >= 0 && gt < T) v = x[((size_t)b * CIN + (c0 + ci)) * T + gt];
      xs[ci][u] = v;
    }
    // stage w chunk, transposed: ws_t[r][col], r = ci*K+dk (48 contiguous in w)
    for (int idx = tid; idx < CI * K * 64; idx += 256) {
      int r = idx >> 6, col = idx & 63;
      int co = co0 + col;
      ws_t[r][col] = (co < Cout) ? w[((size_t)co * CIN + c0) * K + r] : 0.f;
    }
    __syncthreads();
    #pragma unroll
    for (int ci = 0; ci < CI; ++ci) {
      float xv[4 + 2 * PAD];
      const float4 xa = *(const float4*)&xs[ci][tx * 4];
      xv[0] = xa.x; xv[1] = xa.y; xv[2] = xa.z; xv[3] = xa.w;
      if (K == 3) {
        const float2 xb = *(const float2*)&xs[ci][tx * 4 + 4];
        xv[4] = xb.x; xv[5] = xb.y;
      }
      #pragma unroll
      for (int dk = 0; dk < K; ++dk) {
        const float4 wv = *(const float4*)&ws_t[ci * K + dk][ty * 4];
        const float wr[4] = {wv.x, wv.y, wv.z, wv.w};
        #pragma unroll
        for (int i = 0; i < 4; ++i)
          #pragma unroll
          for (int j = 0; j < 4; ++j)
            acc[i][j] = fmaf(wr[i], xv[j + dk], acc[i][j]);
      }
    }
  }
  // epilogue
  #pragma unroll
  for (int i = 0; i < 4; ++i) {
    int co = co0 + ty * 4 + i;
    if (co >= Cout) continue;
    float bv = bias[co];
    #pragma unroll
    for (int j = 0; j < 4; ++j) {
      int t = t0 + tx * 4 + j;
      if (t >= T) continue;
      float v = acc[i][j] + bv;
      if (RELU) v = fmaxf(v, 0.f);
      y[((size_t)b * Cout + co) * T + t] = v;
    }
  }
}

// ---------------------------------------------------------------------------
// Fused attention: qk GEMM (C=80) + q2/k2 + log_softmax over t2 + log(prior).
// Block: (b, 16 t1 rows); thread = one t2 column (200 active of 256).
// ---------------------------------------------------------------------------
__global__ __launch_bounds__(256) void attn_kernel(
    const float* __restrict__ q,      // (B,80,800)
    const float* __restrict__ k,      // (B,80,200)
    const float* __restrict__ prior,  // (B,800,200)
    float* __restrict__ out)          // (B,1,800,200)
{
  const int b   = blockIdx.y;
  const int r0  = blockIdx.x * 16;
  const int tid = threadIdx.x;
  const int t2  = tid;

  __shared__ __align__(16) float qs[80][16];
  __shared__ __align__(16) float ks[16][200];
  __shared__ __align__(16) float ls[16][200];
  __shared__ float q2s[16];
  __shared__ float rlse[16];

  for (int idx = tid; idx < 80 * 16; idx += 256) {
    int c = idx >> 4, i = idx & 15;
    qs[c][i] = q[((size_t)b * 80 + c) * 800 + r0 + i];
  }

  float acc[16];
  #pragma unroll
  for (int i = 0; i < 16; ++i) acc[i] = 0.f;
  float k2 = 0.f;

  for (int c0 = 0; c0 < 80; c0 += 16) {
    __syncthreads();
    for (int idx = tid; idx < 16 * 200; idx += 256) {
      int c = idx / 200, t = idx - c * 200;
      ks[c][t] = k[((size_t)b * 80 + (c0 + c)) * 200 + t];
    }
    __syncthreads();
    if (t2 < 200) {
      #pragma unroll
      for (int c = 0; c < 16; ++c) {
        float kv = ks[c][t2];
        k2 = fmaf(kv, kv, k2);
        #pragma unroll
        for (int i = 0; i < 16; ++i)
          acc[i] = fmaf(qs[c0 + c][i], kv, acc[i]);
      }
    }
  }

  __syncthreads();
  if (tid < 16) {
    float s = 0.f;
    for (int c = 0; c < 80; ++c) { float v = qs[c][tid]; s = fmaf(v, v, s); }
    q2s[tid] = s;
  }
  __syncthreads();

  if (t2 < 200) {
    #pragma unroll
    for (int i = 0; i < 16; ++i)
      ls[i][t2] = -0.0005f * (q2s[i] + k2 - 2.f * acc[i]);
  }
  __syncthreads();

  // per-row max / log-sum-exp: wave w handles rows 4w..4w+3
  const int wave = tid >> 6, lane = tid & 63;
  for (int r = wave * 4; r < wave * 4 + 4; ++r) {
    float m = -INFINITY;
    for (int j = lane; j < 200; j += 64) m = fmaxf(m, ls[r][j]);
    #pragma unroll
    for (int off = 32; off; off >>= 1) m = fmaxf(m, __shfl_xor(m, off));
    float s = 0.f;
    for (int j = lane; j < 200; j += 64) s += __expf(ls[r][j] - m);
    #pragma unroll
    for (int off = 32; off; off >>= 1) s += __shfl_xor(s, off);
    if (lane == 0) rlse[r] = m + __logf(s);
  }
  __syncthreads();

  if (t2 < 200) {
    #pragma unroll
    for (int i = 0; i < 16; ++i) {
      size_t o = ((size_t)b * 800 + (r0 + i)) * 200 + t2;
      out[o] = ls[i][t2] - rlse[i] + __logf(prior[o] + 1e-8f);
    }
  }
}

extern "C" void kernel_launch(void* const* d_in, const int* in_sizes, int n_in,
                              void* d_out, int out_size, void* d_ws, size_t ws_size,
                              hipStream_t stream) {
  const float* queries = (const float*)d_in[0];
  const float* keys    = (const float*)d_in[1];
  const float* prior   = (const float*)d_in[2];
  const float* kw1 = (const float*)d_in[3];
  const float* kb1 = (const float*)d_in[4];
  const float* kw2 = (const float*)d_in[5];
  const float* kb2 = (const float*)d_in[6];
  const float* qw1 = (const float*)d_in[7];
  const float* qb1 = (const float*)d_in[8];
  const float* qw2 = (const float*)d_in[9];
  const float* qb2 = (const float*)d_in[10];
  const float* qw3 = (const float*)d_in[11];
  const float* qb3 = (const float*)d_in[12];
  float* out = (float*)d_out;

  float* ws    = (float*)d_ws;
  float* kbuf1 = ws;                         // 16*512*200 = 1,638,400
  float* qbuf1 = kbuf1 + 16 * 512 * 200;     // 16*160*800 = 2,048,000
  float* qbuf2 = qbuf1 + 16 * 160 * 800;     // 16*80*800  = 1,024,000
  float* kfin  = qbuf2 + 16 * 80 * 800;      // 16*80*200  =   256,000
  float* qfin  = kfin  + 16 * 80 * 200;      // 16*80*800  = 1,024,000
  // total ~24 MB of workspace

  // key encoder
  conv_tile<256, 3, true ><<<dim3(4, 8, 16), 256, 0, stream>>>(keys,  kw1, kb1, kbuf1, 512, 200);
  conv_tile<512, 1, false><<<dim3(4, 2, 16), 256, 0, stream>>>(kbuf1, kw2, kb2, kfin,   80, 200);
  // query encoder
  conv_tile< 80, 3, true ><<<dim3(13, 3, 16), 256, 0, stream>>>(queries, qw1, qb1, qbuf1, 160, 800);
  conv_tile<160, 1, true ><<<dim3(13, 2, 16), 256, 0, stream>>>(qbuf1,   qw2, qb2, qbuf2,  80, 800);
  conv_tile< 80, 1, false><<<dim3(13, 2, 16), 256, 0, stream>>>(qbuf2,   qw3, qb3, qfin,   80, 800);
  // fused qk + log_softmax + prior
  attn_kernel<<<dim3(50, 16), 256, 0, stream>>>(qfin, kfin, prior, out);
}

// Round 2
// 186.747 us; speedup vs baseline: 2.1046x; 2.1046x over previous
//
#include <hip/hip_runtime.h>
#include <cstdint>
#include <cmath>

using short8  = __attribute__((ext_vector_type(8))) short;
using floatx4 = __attribute__((ext_vector_type(4))) float;

__device__ __forceinline__ short f2bf(float f) {
  union { float f; unsigned u; } x; x.f = f;
  unsigned r = x.u + 0x7FFFu + ((x.u >> 16) & 1u);
  return (short)(r >> 16);
}
__device__ __forceinline__ float bf2f(short s) {
  union { unsigned u; float f; } x; x.u = ((unsigned)(unsigned short)s) << 16;
  return x.f;
}

// ---------------------------------------------------------------------------
// cast+transpose: x (B,CIN,T) fp32 -> xT [(b*T+t)][CPITCH] bf16 (pad ci zeroed)
// ---------------------------------------------------------------------------
template<int CIN, int CPITCH>
__global__ __launch_bounds__(256) void cast_transpose(
    const float* __restrict__ x, short* __restrict__ xT, int T)
{
  const int t0 = blockIdx.x * 64, ci0 = blockIdx.y * 32, b = blockIdx.z;
  const int tid = threadIdx.x;
  __shared__ float xs[32][65];
  for (int i = tid; i < 32 * 64; i += 256) {
    int row = i >> 6, col = i & 63;
    float v = 0.f;
    if (ci0 + row < CIN && t0 + col < T)
      v = x[((size_t)b * CIN + ci0 + row) * T + t0 + col];
    xs[row][col] = v;
  }
  __syncthreads();
  int t = tid >> 2, c8 = (tid & 3) * 8;
  if (t0 + t < T) {
    short8 o;
    #pragma unroll
    for (int j = 0; j < 8; ++j) o[j] = f2bf(xs[c8 + j][t]);
    *(short8*)&xT[((size_t)b * T + t0 + t) * CPITCH + ci0 + c8] = o;
  }
}

// ---------------------------------------------------------------------------
// pack all 5 conv weights: w (Cout,CIN,K) fp32 -> wpk [dk][CoPad][CP] bf16
// ---------------------------------------------------------------------------
__global__ __launch_bounds__(256) void pack_weights(
    const float* __restrict__ kw1, const float* __restrict__ kw2,
    const float* __restrict__ qw1, const float* __restrict__ qw2,
    const float* __restrict__ qw3,
    short* w1, short* w2, short* w3, short* w4, short* w5)
{
  const int blk = blockIdx.x, tid = threadIdx.x;
  const float* src; short* dst; int Cout, CIN, K, CoPad, CP, base;
  if      (blk < 384) { src=kw1; dst=w1; Cout=512; CIN=256; K=3; CoPad=512; CP=256; base=0;   }
  else if (blk < 432) { src=kw2; dst=w2; Cout=80;  CIN=512; K=1; CoPad=96;  CP=512; base=384; }
  else if (blk < 477) { src=qw1; dst=w3; Cout=160; CIN=80;  K=3; CoPad=160; CP=96;  base=432; }
  else if (blk < 492) { src=qw2; dst=w4; Cout=80;  CIN=160; K=1; CoPad=96;  CP=160; base=477; }
  else                { src=qw3; dst=w5; Cout=80;  CIN=80;  K=1; CoPad=96;  CP=96;  base=492; }
  int tot = K * CoPad * CP, b0 = (blk - base) * 1024;
  for (int e = 0; e < 4; ++e) {
    int gi = b0 + e * 256 + tid;
    if (gi < tot) {
      int dk  = gi / (CoPad * CP);
      int rem = gi - dk * (CoPad * CP);
      int co  = rem / CP, ci = rem - (rem / CP) * CP;
      float v = (co < Cout && ci < CIN) ? src[((size_t)co * CIN + ci) * K + dk] : 0.f;
      dst[gi] = f2bf(v);
    }
  }
}

// ---------------------------------------------------------------------------
// MFMA conv: yT[b*T+t][co] = relu?(sum_{dk,ci} wpk[dk][co][ci]*xT[b*T+t+dk-PAD][ci] + bias)
// Block 256 = 4 waves; tile TCO x 64t; K-chunks of 32 over ci.
// A(=w) and B(=x) both staged k-contiguous rows, pitch 40 halves (bank-uniform).
// ---------------------------------------------------------------------------
template<int CP, int K, int TCO, bool RELU>
__global__ __launch_bounds__(256) void conv_mfma(
    const short* __restrict__ xT, const short* __restrict__ wpk,
    const float* __restrict__ bias, short* __restrict__ yT,
    int Cout, int T, int CPo)
{
  constexpr int PAD  = (K == 3) ? 1 : 0;
  constexpr int ROWS = 64 + 2 * PAD;
  constexpr int NC   = CP / 32;
  constexpr int WX   = (TCO == 64) ? 2 : 4;   // waves along t
  constexpr int FJ   = (TCO == 64) ? 2 : 1;   // t-frags per wave
  constexpr int PW   = 40;                    // LDS pitch (halves)
  const int b = blockIdx.z, co0 = blockIdx.y * TCO, t0 = blockIdx.x * 64;
  const int CoPad = gridDim.y * TCO;
  const int tid = threadIdx.x, wid = tid >> 6, lane = tid & 63;
  const int wy = wid / WX, wx = wid % WX;
  const int q = lane >> 4, m = lane & 15;

  __shared__ __align__(16) short xs[ROWS * PW];
  __shared__ __align__(16) short as[K * TCO * PW];

  floatx4 acc[2][FJ];
  #pragma unroll
  for (int i = 0; i < 2; ++i)
    #pragma unroll
    for (int j = 0; j < FJ; ++j) acc[i][j] = (floatx4){0.f, 0.f, 0.f, 0.f};

  for (int c0 = 0; c0 < NC; ++c0) {
    __syncthreads();
    for (int i = tid; i < ROWS * 4; i += 256) {
      int row = i >> 2, c8 = (i & 3) * 8;
      int t = t0 + row - PAD;
      int4 v = {0, 0, 0, 0};
      if (t >= 0 && t < T)
        v = *(const int4*)&xT[((size_t)b * T + t) * CP + c0 * 32 + c8];
      *(int4*)&xs[row * PW + c8] = v;
    }
    for (int i = tid; i < K * TCO * 4; i += 256) {
      int row = i >> 2, c8 = (i & 3) * 8;
      int dk = row / TCO, co = row % TCO;
      *(int4*)&as[row * PW + c8] =
          *(const int4*)&wpk[((size_t)(dk * CoPad + co0 + co)) * CP + c0 * 32 + c8];
    }
    __syncthreads();
    #pragma unroll
    for (int dk = 0; dk < K; ++dk) {
      short8 fa0 = *(const short8*)&as[(dk * TCO + wy * 32 + m) * PW + q * 8];
      short8 fa1 = *(const short8*)&as[(dk * TCO + wy * 32 + 16 + m) * PW + q * 8];
      #pragma unroll
      for (int j = 0; j < FJ; ++j) {
        short8 fb = *(const short8*)&xs[(wx * 16 * FJ + j * 16 + m + dk) * PW + q * 8];
        acc[0][j] = __builtin_amdgcn_mfma_f32_16x16x32_bf16(fa0, fb, acc[0][j], 0, 0, 0);
        acc[1][j] = __builtin_amdgcn_mfma_f32_16x16x32_bf16(fa1, fb, acc[1][j], 0, 0, 0);
      }
    }
  }
  // epilogue: D layout col=lane&15 (t), row=q*4+reg (co)  [m89/m91 verified]
  #pragma unroll
  for (int i = 0; i < 2; ++i) {
    #pragma unroll
    for (int j = 0; j < FJ; ++j) {
      #pragma unroll
      for (int r = 0; r < 4; ++r) {
        int co = co0 + wy * 32 + i * 16 + q * 4 + r;
        int t  = t0 + wx * 16 * FJ + j * 16 + m;
        if (t < T && co < CPo) {
          float v = acc[i][j][r] + (co < Cout ? bias[co] : 0.f);
          if (RELU) v = fmaxf(v, 0.f);
          yT[((size_t)b * T + t) * CPo + co] = f2bf(v);
        }
      }
    }
  }
}

// ---------------------------------------------------------------------------
// Attention: S = q.k^T (MFMA, K=96 incl zero pad), L = 0.001*S - 0.0005*k2[t2]
// (q2 term is constant along softmax axis -> cancels), in-register log_softmax
// over 16-lane groups, + log(prior+1e-8). Block: 64 t1 rows x all 200 t2.
// ---------------------------------------------------------------------------
__global__ __launch_bounds__(256) void attn_mfma(
    const short* __restrict__ qT,   // [16*800][96]
    const short* __restrict__ kT,   // [16*200][96]
    const float* __restrict__ prior, float* __restrict__ out)
{
  const int b = blockIdx.y, t1_0 = blockIdx.x * 64;
  const int tid = threadIdx.x, wid = tid >> 6, lane = tid & 63;
  const int q = lane >> 4, m = lane & 15;

  __shared__ __align__(16) short aq[64 * 104];   // q rows, full K=96, pitch 104
  __shared__ __align__(16) short bk[208 * 40];   // k rows, per 32-chunk, pitch 40
  __shared__ float k2s[208];

  floatx4 acc[13];
  #pragma unroll
  for (int f = 0; f < 13; ++f) acc[f] = (floatx4){0.f, 0.f, 0.f, 0.f};

  for (int i = tid; i < 64 * 12; i += 256) {
    int row = i / 12, g = i - (i / 12) * 12;
    int4 v = {0, 0, 0, 0};
    if (t1_0 + row < 800)
      v = *(const int4*)&qT[((size_t)b * 800 + t1_0 + row) * 96 + g * 8];
    *(int4*)&aq[row * 104 + g * 8] = v;
  }

  float k2acc = 0.f;
  for (int c = 0; c < 3; ++c) {
    __syncthreads();
    for (int i = tid; i < 208 * 4; i += 256) {
      int row = i >> 2, g = i & 3;
      int4 v = {0, 0, 0, 0};
      if (row < 200)
        v = *(const int4*)&kT[((size_t)b * 200 + row) * 96 + c * 32 + g * 8];
      *(int4*)&bk[row * 40 + g * 8] = v;
    }
    __syncthreads();
    if (tid < 208) {
      #pragma unroll
      for (int g = 0; g < 4; ++g) {
        short8 s = *(const short8*)&bk[tid * 40 + g * 8];
        #pragma unroll
        for (int j = 0; j < 8; ++j) { float f = bf2f(s[j]); k2acc = fmaf(f, f, k2acc); }
      }
    }
    short8 fa = *(const short8*)&aq[(wid * 16 + m) * 104 + c * 32 + q * 8];
    #pragma unroll
    for (int f = 0; f < 13; ++f) {
      short8 fb = *(const short8*)&bk[(f * 16 + m) * 40 + q * 8];
      acc[f] = __builtin_amdgcn_mfma_f32_16x16x32_bf16(fa, fb, acc[f], 0, 0, 0);
    }
  }
  if (tid < 208) k2s[tid] = k2acc;
  __syncthreads();

  float k2v[13];
  #pragma unroll
  for (int f = 0; f < 13; ++f) k2v[f] = k2s[f * 16 + m];

  // logits in place; row = q*4+r (t1), col = f*16+m (t2)
  float mx[4] = {-INFINITY, -INFINITY, -INFINITY, -INFINITY};
  #pragma unroll
  for (int f = 0; f < 13; ++f) {
    bool valid = (f * 16 + m) < 200;
    #pragma unroll
    for (int r = 0; r < 4; ++r) {
      float v = valid ? (0.001f * acc[f][r] - 0.0005f * k2v[f]) : -INFINITY;
      acc[f][r] = v;
      mx[r] = fmaxf(mx[r], v);
    }
  }
  #pragma unroll
  for (int msk = 1; msk < 16; msk <<= 1)
    #pragma unroll
    for (int r = 0; r < 4; ++r) mx[r] = fmaxf(mx[r], __shfl_xor(mx[r], msk));
  float sm[4] = {0.f, 0.f, 0.f, 0.f};
  #pragma unroll
  for (int f = 0; f < 13; ++f)
    #pragma unroll
    for (int r = 0; r < 4; ++r) sm[r] += __expf(acc[f][r] - mx[r]);
  #pragma unroll
  for (int msk = 1; msk < 16; msk <<= 1)
    #pragma unroll
    for (int r = 0; r < 4; ++r) sm[r] += __shfl_xor(sm[r], msk);
  float lse[4];
  #pragma unroll
  for (int r = 0; r < 4; ++r) lse[r] = mx[r] + __logf(sm[r]);

  #pragma unroll
  for (int f = 0; f < 13; ++f) {
    int col = f * 16 + m;
    if (col < 200) {
      #pragma unroll
      for (int r = 0; r < 4; ++r) {
        int t1 = t1_0 + wid * 16 + q * 4 + r;
        if (t1 < 800) {
          size_t o = ((size_t)b * 800 + t1) * 200 + col;
          out[o] = acc[f][r] - lse[r] + __logf(prior[o] + 1e-8f);
        }
      }
    }
  }
}

extern "C" void kernel_launch(void* const* d_in, const int* in_sizes, int n_in,
                              void* d_out, int out_size, void* d_ws, size_t ws_size,
                              hipStream_t stream) {
  const float* queries = (const float*)d_in[0];
  const float* keys    = (const float*)d_in[1];
  const float* prior   = (const float*)d_in[2];
  const float* kw1 = (const float*)d_in[3];
  const float* kb1 = (const float*)d_in[4];
  const float* kw2 = (const float*)d_in[5];
  const float* kb2 = (const float*)d_in[6];
  const float* qw1 = (const float*)d_in[7];
  const float* qb1 = (const float*)d_in[8];
  const float* qw2 = (const float*)d_in[9];
  const float* qb2 = (const float*)d_in[10];
  const float* qw3 = (const float*)d_in[11];
  const float* qb3 = (const float*)d_in[12];
  float* out = (float*)d_out;

  char* p = (char*)d_ws;
  short* kT0 = (short*)p;                 p += (size_t)3200  * 256 * 2;  // keys^T
  short* qT0 = (short*)p;                 p += (size_t)12800 * 96  * 2;  // queries^T
  short* w1  = (short*)p;                 p += (size_t)3 * 512 * 256 * 2;
  short* w2  = (short*)p;                 p += (size_t)96 * 512 * 2;
  short* w3  = (short*)p;                 p += (size_t)3 * 160 * 96 * 2;
  short* w4  = (short*)p;                 p += (size_t)96 * 160 * 2;
  short* w5  = (short*)p;                 p += (size_t)96 * 96 * 2;
  short* kT1 = (short*)p;                 p += (size_t)3200  * 512 * 2;
  short* qT1 = (short*)p;                 p += (size_t)12800 * 160 * 2;
  short* kF  = (short*)p;                 p += (size_t)3200  * 96 * 2;
  short* qT2 = (short*)p;                 p += (size_t)12800 * 96 * 2;
  short* qF  = (short*)p;                 p += (size_t)12800 * 96 * 2;

  cast_transpose<256, 256><<<dim3(4, 8, 16),  256, 0, stream>>>(keys,    kT0, 200);
  cast_transpose< 80,  96><<<dim3(13, 3, 16), 256, 0, stream>>>(queries, qT0, 800);
  pack_weights<<<dim3(501), 256, 0, stream>>>(kw1, kw2, qw1, qw2, qw3, w1, w2, w3, w4, w5);

  conv_mfma<256, 3, 64, true ><<<dim3(4, 8, 16),  256, 0, stream>>>(kT0, w1, kb1, kT1, 512, 200, 512);
  conv_mfma<512, 1, 32, false><<<dim3(4, 3, 16),  256, 0, stream>>>(kT1, w2, kb2, kF,   80, 200,  96);
  conv_mfma< 96, 3, 32, true ><<<dim3(13, 5, 16), 256, 0, stream>>>(qT0, w3, qb1, qT1, 160, 800, 160);
  conv_mfma<160, 1, 32, true ><<<dim3(13, 3, 16), 256, 0, stream>>>(qT1, w4, qb2, qT2,  80, 800,  96);
  conv_mfma< 96, 1, 32, false><<<dim3(13, 3, 16), 256, 0, stream>>>(qT2, w5, qb3, qF,   80, 800,  96);

  attn_mfma<<<dim3(13, 16), 256, 0, stream>>>(qF, kF, prior, out);
}

// Round 3
// 169.514 us; speedup vs baseline: 2.3186x; 1.1017x over previous
//
#include <hip/hip_runtime.h>
#include <cstdint>
#include <cmath>

using short8  = __attribute__((ext_vector_type(8))) short;
using short4v = __attribute__((ext_vector_type(4))) short;
using floatx4 = __attribute__((ext_vector_type(4))) float;

__device__ __forceinline__ short f2bf(float f) {
  union { float f; unsigned u; } x; x.f = f;
  unsigned r = x.u + 0x7FFFu + ((x.u >> 16) & 1u);
  return (short)(r >> 16);
}

// ===========================================================================
// prep: block-range dispatch
//   [0,512)     cast keys    (16,256,200) fp32 -> kT0 [b*200+t][256] bf16
//   [512,1136)  cast queries (16,80,800)  fp32 -> qT0 [b*800+t][96]  bf16 (pad 0)
//   [1136,1649) pack 5 weights to bf16 [dk][CoPad][CiPad] (pads zeroed)
// ===========================================================================
__global__ __launch_bounds__(256) void prep_kernel(
    const float* __restrict__ keys, const float* __restrict__ queries,
    const float* __restrict__ kw1, const float* __restrict__ kw2,
    const float* __restrict__ qw1, const float* __restrict__ qw2,
    const float* __restrict__ qw3,
    short* __restrict__ kT0, short* __restrict__ qT0,
    short* __restrict__ w1, short* __restrict__ w2, short* __restrict__ w3,
    short* __restrict__ w4, short* __restrict__ w5)
{
  const int bid = blockIdx.x, tid = threadIdx.x;
  __shared__ float xs[32][65];

  if (bid < 1136) {
    // ---- cast+transpose ----
    const float* src; short* dst; int CIN, T, CP, bx, by, b;
    if (bid < 512) {
      src = keys; dst = kT0; CIN = 256; T = 200; CP = 256;
      bx = bid & 3; by = (bid >> 2) & 7; b = bid >> 5;
    } else {
      int b2 = bid - 512;
      src = queries; dst = qT0; CIN = 80; T = 800; CP = 96;
      bx = b2 % 13; by = (b2 / 13) % 3; b = b2 / 39;
    }
    const int t0 = bx * 64, ci0 = by * 32;
    for (int i = tid; i < 32 * 64; i += 256) {
      int row = i >> 6, col = i & 63;
      float v = 0.f;
      if (ci0 + row < CIN && t0 + col < T)
        v = src[((size_t)b * CIN + ci0 + row) * T + t0 + col];
      xs[row][col] = v;
    }
    __syncthreads();
    int t = tid >> 2, c8 = (tid & 3) * 8;
    if (t0 + t < T) {
      short8 o;
      #pragma unroll
      for (int j = 0; j < 8; ++j) o[j] = f2bf(xs[c8 + j][t]);
      *(short8*)&dst[((size_t)b * T + t0 + t) * CP + ci0 + c8] = o;
    }
  } else {
    // ---- weight pack ----
    int blk = bid - 1136;
    const float* src; short* dst; int base, tot;
    int CoP, CiP, Cout, CIN, K;
    if      (blk < 384) { src=kw1; dst=w1; base=0;   CoP=512; CiP=256; Cout=512; CIN=256; K=3; }
    else if (blk < 432) { src=kw2; dst=w2; base=384; CoP=96;  CiP=512; Cout=80;  CIN=512; K=1; }
    else if (blk < 486) { src=qw1; dst=w3; base=432; CoP=192; CiP=96;  Cout=160; CIN=80;  K=3; }
    else if (blk < 504) { src=qw2; dst=w4; base=486; CoP=96;  CiP=192; Cout=80;  CIN=160; K=1; }
    else                { src=qw3; dst=w5; base=504; CoP=96;  CiP=96;  Cout=80;  CIN=80;  K=1; }
    tot = K * CoP * CiP;
    int b0 = (blk - base) * 1024;
    for (int e = 0; e < 4; ++e) {
      int gi = b0 + e * 256 + tid;
      if (gi < tot) {
        int dk  = gi / (CoP * CiP);
        int rem = gi - dk * (CoP * CiP);
        int co  = rem / CiP, ci = rem - (rem / CiP) * CiP;
        float v = (co < Cout && ci < CIN) ? src[((size_t)co * CIN + ci) * K + dk] : 0.f;
        dst[gi] = f2bf(v);
      }
    }
  }
}

// ===========================================================================
// encoders: blocks [0,64) = key chain, [64,272) = query chain. 256 thr = 4 waves.
// key  (per 64-t tile): conv 3x 256->512 +ReLU (two 256-ci halves, y1 in LDS)
//                       then 1x 512->96(80) accumulated across halves -> kF
// query(per 64-t tile): conv 3x 96(80)->192(160)+ReLU -> y1 LDS
//                       1x 192->96(80)+ReLU -> y2 LDS ; 1x 96->96(80) -> qF
// Weights read as A-frags directly from global (L2-resident).
// MFMA convention (verified r2): fa=W-rows(co), fb=X-rows(t);
//   D: col=lane&15 -> t, row=(lane>>4)*4+reg -> co.
// ===========================================================================
__global__ __launch_bounds__(256) void encoders_kernel(
    const short* __restrict__ kT0, const short* __restrict__ qT0,
    const short* __restrict__ w1, const short* __restrict__ w2,
    const short* __restrict__ w3, const short* __restrict__ w4,
    const short* __restrict__ w5,
    const float* __restrict__ kb1, const float* __restrict__ kb2,
    const float* __restrict__ qb1, const float* __restrict__ qb2,
    const float* __restrict__ qb3,
    short* __restrict__ kF, short* __restrict__ qF)
{
  __shared__ __align__(16) short smem[25680];
  const int tid = threadIdx.x, wid = tid >> 6, lane = tid & 63;
  const int q = lane >> 4, m = lane & 15;
  short* xs = smem;           // [66][40]

  if (blockIdx.x < 64) {
    // ----------------- KEY CHAIN -----------------
    const int b = blockIdx.x >> 2, t0 = (blockIdx.x & 3) * 64;
    short* y1c = smem + 2640;   // [8][64][40] (one 256-ci half)

    floatx4 acc2[6];
    #pragma unroll
    for (int f = 0; f < 6; ++f) acc2[f] = (floatx4){0.f, 0.f, 0.f, 0.f};

    for (int half = 0; half < 2; ++half) {
      floatx4 acc1[4][4];
      #pragma unroll
      for (int f = 0; f < 4; ++f)
        #pragma unroll
        for (int tf = 0; tf < 4; ++tf) acc1[f][tf] = (floatx4){0.f, 0.f, 0.f, 0.f};

      for (int c0 = 0; c0 < 8; ++c0) {
        __syncthreads();
        // stage x chunk (rows t0-1 .. t0+64, 32 ci)
        for (int i = tid; i < 66 * 4; i += 256) {
          int row = i >> 2, c8 = (i & 3) * 8;
          int t = t0 + row - 1;
          int4 v = {0, 0, 0, 0};
          if (t >= 0 && t < 200)
            v = *(const int4*)&kT0[((size_t)b * 200 + t) * 256 + c0 * 32 + c8];
          *(int4*)&xs[row * 40 + c8] = v;
        }
        __syncthreads();
        #pragma unroll
        for (int dk = 0; dk < 3; ++dk) {
          short8 fa[4];
          #pragma unroll
          for (int f = 0; f < 4; ++f)
            fa[f] = *(const short8*)&w1[((size_t)(dk * 512 + half * 256 + wid * 64 + f * 16 + m)) * 256
                                        + c0 * 32 + q * 8];
          #pragma unroll
          for (int tf = 0; tf < 4; ++tf) {
            short8 fb = *(const short8*)&xs[(tf * 16 + m + dk) * 40 + q * 8];
            #pragma unroll
            for (int f = 0; f < 4; ++f)
              acc1[f][tf] = __builtin_amdgcn_mfma_f32_16x16x32_bf16(fa[f], fb, acc1[f][tf], 0, 0, 0);
          }
        }
      }
      // conv1 epilogue -> y1c (relu + bias)
      __syncthreads();
      #pragma unroll
      for (int f = 0; f < 4; ++f) {
        #pragma unroll
        for (int tf = 0; tf < 4; ++tf) {
          int co_l = wid * 64 + f * 16 + q * 4;
          int co   = half * 256 + co_l;
          int t    = tf * 16 + m;
          short4v o;
          #pragma unroll
          for (int r = 0; r < 4; ++r)
            o[r] = f2bf(fmaxf(acc1[f][tf][r] + kb1[co + r], 0.f));
          *(short4v*)&y1c[(co_l >> 5) * 2560 + t * 40 + (co_l & 31)] = o;
        }
      }
      __syncthreads();
      // conv2 partial accumulation over this half's 8 ci-chunks
      #pragma unroll
      for (int c = 0; c < 8; ++c) {
        short8 fb = *(const short8*)&y1c[c * 2560 + (wid * 16 + m) * 40 + q * 8];
        #pragma unroll
        for (int f = 0; f < 6; ++f) {
          short8 fa = *(const short8*)&w2[((size_t)(f * 16 + m)) * 512 + half * 256 + c * 32 + q * 8];
          acc2[f] = __builtin_amdgcn_mfma_f32_16x16x32_bf16(fa, fb, acc2[f], 0, 0, 0);
        }
      }
    }
    // kF epilogue
    int t = t0 + wid * 16 + m;
    if (t < 200) {
      #pragma unroll
      for (int f = 0; f < 6; ++f) {
        int co = f * 16 + q * 4;
        short4v o;
        #pragma unroll
        for (int r = 0; r < 4; ++r) {
          float bv = (co + r < 80) ? kb2[co + r] : 0.f;
          o[r] = f2bf(acc2[f][r] + bv);
        }
        *(short4v*)&kF[((size_t)b * 200 + t) * 96 + co] = o;
      }
    }
  } else {
    // ----------------- QUERY CHAIN -----------------
    const int qbid = blockIdx.x - 64;
    const int b = qbid / 13, t0 = (qbid % 13) * 64;
    short* y1c = smem + 2640;    // [6][64][40]
    short* y2c = smem + 18000;   // [3][64][40]

    // conv1: 96(80) -> 192(160), k=3
    floatx4 accq[3][4];
    #pragma unroll
    for (int f = 0; f < 3; ++f)
      #pragma unroll
      for (int tf = 0; tf < 4; ++tf) accq[f][tf] = (floatx4){0.f, 0.f, 0.f, 0.f};

    for (int c0 = 0; c0 < 3; ++c0) {
      __syncthreads();
      for (int i = tid; i < 66 * 4; i += 256) {
        int row = i >> 2, c8 = (i & 3) * 8;
        int t = t0 + row - 1;
        int4 v = {0, 0, 0, 0};
        if (t >= 0 && t < 800)
          v = *(const int4*)&qT0[((size_t)b * 800 + t) * 96 + c0 * 32 + c8];
        *(int4*)&xs[row * 40 + c8] = v;
      }
      __syncthreads();
      #pragma unroll
      for (int dk = 0; dk < 3; ++dk) {
        short8 fa[3];
        #pragma unroll
        for (int f = 0; f < 3; ++f)
          fa[f] = *(const short8*)&w3[((size_t)(dk * 192 + wid * 48 + f * 16 + m)) * 96
                                      + c0 * 32 + q * 8];
        #pragma unroll
        for (int tf = 0; tf < 4; ++tf) {
          short8 fb = *(const short8*)&xs[(tf * 16 + m + dk) * 40 + q * 8];
          #pragma unroll
          for (int f = 0; f < 3; ++f)
            accq[f][tf] = __builtin_amdgcn_mfma_f32_16x16x32_bf16(fa[f], fb, accq[f][tf], 0, 0, 0);
        }
      }
    }
    __syncthreads();
    #pragma unroll
    for (int f = 0; f < 3; ++f) {
      #pragma unroll
      for (int tf = 0; tf < 4; ++tf) {
        int co = wid * 48 + f * 16 + q * 4;
        int t  = tf * 16 + m;
        short4v o;
        #pragma unroll
        for (int r = 0; r < 4; ++r) {
          float bv = (co + r < 160) ? qb1[co + r] : 0.f;
          o[r] = f2bf(fmaxf(accq[f][tf][r] + bv, 0.f));
        }
        *(short4v*)&y1c[(co >> 5) * 2560 + t * 40 + (co & 31)] = o;
      }
    }
    __syncthreads();

    // conv2: 192(160) -> 96(80), k=1 ; wave handles t-frag wid
    floatx4 acc2q[6];
    #pragma unroll
    for (int f = 0; f < 6; ++f) acc2q[f] = (floatx4){0.f, 0.f, 0.f, 0.f};
    #pragma unroll
    for (int c = 0; c < 6; ++c) {
      short8 fb = *(const short8*)&y1c[c * 2560 + (wid * 16 + m) * 40 + q * 8];
      #pragma unroll
      for (int f = 0; f < 6; ++f) {
        short8 fa = *(const short8*)&w4[((size_t)(f * 16 + m)) * 192 + c * 32 + q * 8];
        acc2q[f] = __builtin_amdgcn_mfma_f32_16x16x32_bf16(fa, fb, acc2q[f], 0, 0, 0);
      }
    }
    #pragma unroll
    for (int f = 0; f < 6; ++f) {
      int co = f * 16 + q * 4;
      int t  = wid * 16 + m;
      short4v o;
      #pragma unroll
      for (int r = 0; r < 4; ++r) {
        float bv = (co + r < 80) ? qb2[co + r] : 0.f;
        o[r] = f2bf(fmaxf(acc2q[f][r] + bv, 0.f));
      }
      *(short4v*)&y2c[(co >> 5) * 2560 + t * 40 + (co & 31)] = o;
    }
    __syncthreads();

    // conv3: 96(80) -> 96(80), k=1
    floatx4 acc3q[6];
    #pragma unroll
    for (int f = 0; f < 6; ++f) acc3q[f] = (floatx4){0.f, 0.f, 0.f, 0.f};
    #pragma unroll
    for (int c = 0; c < 3; ++c) {
      short8 fb = *(const short8*)&y2c[c * 2560 + (wid * 16 + m) * 40 + q * 8];
      #pragma unroll
      for (int f = 0; f < 6; ++f) {
        short8 fa = *(const short8*)&w5[((size_t)(f * 16 + m)) * 96 + c * 32 + q * 8];
        acc3q[f] = __builtin_amdgcn_mfma_f32_16x16x32_bf16(fa, fb, acc3q[f], 0, 0, 0);
      }
    }
    int t = t0 + wid * 16 + m;
    if (t < 800) {
      #pragma unroll
      for (int f = 0; f < 6; ++f) {
        int co = f * 16 + q * 4;
        short4v o;
        #pragma unroll
        for (int r = 0; r < 4; ++r) {
          float bv = (co + r < 80) ? qb3[co + r] : 0.f;
          o[r] = f2bf(acc3q[f][r] + bv);
        }
        *(short4v*)&qF[((size_t)b * 800 + t) * 96 + co] = o;
      }
    }
  }
}

// ===========================================================================
// Attention (unchanged, verified r2): S = q.k^T (K=96 w/ zero pad),
// L = 0.001*S - 0.0005*k2[t2] (q2 cancels in log_softmax), in-register
// log_softmax over 16-lane groups, + log(prior+1e-8).
// ===========================================================================
__global__ __launch_bounds__(256) void attn_mfma(
    const short* __restrict__ qT, const short* __restrict__ kT,
    const float* __restrict__ prior, float* __restrict__ out)
{
  const int b = blockIdx.y, t1_0 = blockIdx.x * 64;
  const int tid = threadIdx.x, wid = tid >> 6, lane = tid & 63;
  const int q = lane >> 4, m = lane & 15;

  __shared__ __align__(16) short aq[64 * 104];
  __shared__ __align__(16) short bk[208 * 40];
  __shared__ float k2s[208];

  floatx4 acc[13];
  #pragma unroll
  for (int f = 0; f < 13; ++f) acc[f] = (floatx4){0.f, 0.f, 0.f, 0.f};

  for (int i = tid; i < 64 * 12; i += 256) {
    int row = i / 12, g = i - (i / 12) * 12;
    int4 v = {0, 0, 0, 0};
    if (t1_0 + row < 800)
      v = *(const int4*)&qT[((size_t)b * 800 + t1_0 + row) * 96 + g * 8];
    *(int4*)&aq[row * 104 + g * 8] = v;
  }

  float k2acc = 0.f;
  for (int c = 0; c < 3; ++c) {
    __syncthreads();
    for (int i = tid; i < 208 * 4; i += 256) {
      int row = i >> 2, g = i & 3;
      int4 v = {0, 0, 0, 0};
      if (row < 200)
        v = *(const int4*)&kT[((size_t)b * 200 + row) * 96 + c * 32 + g * 8];
      *(int4*)&bk[row * 40 + g * 8] = v;
    }
    __syncthreads();
    if (tid < 208) {
      #pragma unroll
      for (int g = 0; g < 4; ++g) {
        short8 s = *(const short8*)&bk[tid * 40 + g * 8];
        #pragma unroll
        for (int j = 0; j < 8; ++j) {
          union { unsigned u; float f; } x; x.u = ((unsigned)(unsigned short)s[j]) << 16;
          k2acc = fmaf(x.f, x.f, k2acc);
        }
      }
    }
    short8 fa = *(const short8*)&aq[(wid * 16 + m) * 104 + c * 32 + q * 8];
    #pragma unroll
    for (int f = 0; f < 13; ++f) {
      short8 fb = *(const short8*)&bk[(f * 16 + m) * 40 + q * 8];
      acc[f] = __builtin_amdgcn_mfma_f32_16x16x32_bf16(fa, fb, acc[f], 0, 0, 0);
    }
  }
  if (tid < 208) k2s[tid] = k2acc;
  __syncthreads();

  float k2v[13];
  #pragma unroll
  for (int f = 0; f < 13; ++f) k2v[f] = k2s[f * 16 + m];

  float mx[4] = {-INFINITY, -INFINITY, -INFINITY, -INFINITY};
  #pragma unroll
  for (int f = 0; f < 13; ++f) {
    bool valid = (f * 16 + m) < 200;
    #pragma unroll
    for (int r = 0; r < 4; ++r) {
      float v = valid ? (0.001f * acc[f][r] - 0.0005f * k2v[f]) : -INFINITY;
      acc[f][r] = v;
      mx[r] = fmaxf(mx[r], v);
    }
  }
  #pragma unroll
  for (int msk = 1; msk < 16; msk <<= 1)
    #pragma unroll
    for (int r = 0; r < 4; ++r) mx[r] = fmaxf(mx[r], __shfl_xor(mx[r], msk));
  float sm[4] = {0.f, 0.f, 0.f, 0.f};
  #pragma unroll
  for (int f = 0; f < 13; ++f)
    #pragma unroll
    for (int r = 0; r < 4; ++r) sm[r] += __expf(acc[f][r] - mx[r]);
  #pragma unroll
  for (int msk = 1; msk < 16; msk <<= 1)
    #pragma unroll
    for (int r = 0; r < 4; ++r) sm[r] += __shfl_xor(sm[r], msk);
  float lse[4];
  #pragma unroll
  for (int r = 0; r < 4; ++r) lse[r] = mx[r] + __logf(sm[r]);

  #pragma unroll
  for (int f = 0; f < 13; ++f) {
    int col = f * 16 + m;
    if (col < 200) {
      #pragma unroll
      for (int r = 0; r < 4; ++r) {
        int t1 = t1_0 + wid * 16 + q * 4 + r;
        if (t1 < 800) {
          size_t o = ((size_t)b * 800 + t1) * 200 + col;
          out[o] = acc[f][r] - lse[r] + __logf(prior[o] + 1e-8f);
        }
      }
    }
  }
}

extern "C" void kernel_launch(void* const* d_in, const int* in_sizes, int n_in,
                              void* d_out, int out_size, void* d_ws, size_t ws_size,
                              hipStream_t stream) {
  const float* queries = (const float*)d_in[0];
  const float* keys    = (const float*)d_in[1];
  const float* prior   = (const float*)d_in[2];
  const float* kw1 = (const float*)d_in[3];
  const float* kb1 = (const float*)d_in[4];
  const float* kw2 = (const float*)d_in[5];
  const float* kb2 = (const float*)d_in[6];
  const float* qw1 = (const float*)d_in[7];
  const float* qb1 = (const float*)d_in[8];
  const float* qw2 = (const float*)d_in[9];
  const float* qb2 = (const float*)d_in[10];
  const float* qw3 = (const float*)d_in[11];
  const float* qb3 = (const float*)d_in[12];
  float* out = (float*)d_out;

  short* p = (short*)d_ws;
  short* kT0 = p;  p += (size_t)3200 * 256;
  short* qT0 = p;  p += (size_t)12800 * 96;
  short* w1  = p;  p += (size_t)3 * 512 * 256;
  short* w2  = p;  p += (size_t)96 * 512;
  short* w3  = p;  p += (size_t)3 * 192 * 96;
  short* w4  = p;  p += (size_t)96 * 192;
  short* w5  = p;  p += (size_t)96 * 96;
  short* kF  = p;  p += (size_t)3200 * 96;
  short* qF  = p;  p += (size_t)12800 * 96;

  prep_kernel<<<dim3(1649), 256, 0, stream>>>(keys, queries, kw1, kw2, qw1, qw2, qw3,
                                              kT0, qT0, w1, w2, w3, w4, w5);
  encoders_kernel<<<dim3(272), 256, 0, stream>>>(kT0, qT0, w1, w2, w3, w4, w5,
                                                 kb1, kb2, qb1, qb2, qb3, kF, qF);
  attn_mfma<<<dim3(13, 16), 256, 0, stream>>>(qF, kF, prior, out);
}

// Round 4
// 152.729 us; speedup vs baseline: 2.5734x; 1.1099x over previous
//
#include <hip/hip_runtime.h>
#include <cstdint>
#include <cmath>

using short8  = __attribute__((ext_vector_type(8))) short;
using short4v = __attribute__((ext_vector_type(4))) short;
using floatx4 = __attribute__((ext_vector_type(4))) float;

__device__ __forceinline__ short f2bf(float f) {
  union { float f; unsigned u; } x; x.f = f;
  unsigned r = x.u + 0x7FFFu + ((x.u >> 16) & 1u);
  return (short)(r >> 16);
}

// ===========================================================================
// prep (verified r3): cast/transpose keys+queries, pack 5 weights to bf16.
// ===========================================================================
__global__ __launch_bounds__(256) void prep_kernel(
    const float* __restrict__ keys, const float* __restrict__ queries,
    const float* __restrict__ kw1, const float* __restrict__ kw2,
    const float* __restrict__ qw1, const float* __restrict__ qw2,
    const float* __restrict__ qw3,
    short* __restrict__ kT0, short* __restrict__ qT0,
    short* __restrict__ w1, short* __restrict__ w2, short* __restrict__ w3,
    short* __restrict__ w4, short* __restrict__ w5)
{
  const int bid = blockIdx.x, tid = threadIdx.x;
  __shared__ float xs[32][65];

  if (bid < 1136) {
    const float* src; short* dst; int CIN, T, CP, bx, by, b;
    if (bid < 512) {
      src = keys; dst = kT0; CIN = 256; T = 200; CP = 256;
      bx = bid & 3; by = (bid >> 2) & 7; b = bid >> 5;
    } else {
      int b2 = bid - 512;
      src = queries; dst = qT0; CIN = 80; T = 800; CP = 96;
      bx = b2 % 13; by = (b2 / 13) % 3; b = b2 / 39;
    }
    const int t0 = bx * 64, ci0 = by * 32;
    for (int i = tid; i < 32 * 64; i += 256) {
      int row = i >> 6, col = i & 63;
      float v = 0.f;
      if (ci0 + row < CIN && t0 + col < T)
        v = src[((size_t)b * CIN + ci0 + row) * T + t0 + col];
      xs[row][col] = v;
    }
    __syncthreads();
    int t = tid >> 2, c8 = (tid & 3) * 8;
    if (t0 + t < T) {
      short8 o;
      #pragma unroll
      for (int j = 0; j < 8; ++j) o[j] = f2bf(xs[c8 + j][t]);
      *(short8*)&dst[((size_t)b * T + t0 + t) * CP + ci0 + c8] = o;
    }
  } else {
    int blk = bid - 1136;
    const float* src; short* dst; int base;
    int CoP, CiP, Cout, CIN, K;
    if      (blk < 384) { src=kw1; dst=w1; base=0;   CoP=512; CiP=256; Cout=512; CIN=256; K=3; }
    else if (blk < 432) { src=kw2; dst=w2; base=384; CoP=96;  CiP=512; Cout=80;  CIN=512; K=1; }
    else if (blk < 486) { src=qw1; dst=w3; base=432; CoP=192; CiP=96;  Cout=160; CIN=80;  K=3; }
    else if (blk < 504) { src=qw2; dst=w4; base=486; CoP=96;  CiP=192; Cout=80;  CIN=160; K=1; }
    else                { src=qw3; dst=w5; base=504; CoP=96;  CiP=96;  Cout=80;  CIN=80;  K=1; }
    int tot = K * CoP * CiP;
    int b0 = (blk - base) * 1024;
    for (int e = 0; e < 4; ++e) {
      int gi = b0 + e * 256 + tid;
      if (gi < tot) {
        int dk  = gi / (CoP * CiP);
        int rem = gi - dk * (CoP * CiP);
        int co  = rem / CiP, ci = rem - (rem / CiP) * CiP;
        float v = (co < Cout && ci < CIN) ? src[((size_t)co * CIN + ci) * K + dk] : 0.f;
        dst[gi] = f2bf(v);
      }
    }
  }
}

// ===========================================================================
// conv_k3: blocks [0,512) = key conv1 (256->512 k3 +ReLU), co-parallel tiled
//          (r2-verified conv_mfma, TCO=64, LDS-staged weights) -> kT1.
//          blocks [512,720) = full query chain per 64-t tile (r3-verified)
//          -> qF.
// ===========================================================================
__global__ __launch_bounds__(256) void conv_k3_kernel(
    const short* __restrict__ kT0, const short* __restrict__ qT0,
    const short* __restrict__ w1, const short* __restrict__ w3,
    const short* __restrict__ w4, const short* __restrict__ w5,
    const float* __restrict__ kb1, const float* __restrict__ qb1,
    const float* __restrict__ qb2, const float* __restrict__ qb3,
    short* __restrict__ kT1, short* __restrict__ qF)
{
  __shared__ __align__(16) short smem[25680];
  const int tid = threadIdx.x, wid = tid >> 6, lane = tid & 63;
  const int q = lane >> 4, m = lane & 15;
  short* xs = smem;   // [66][40]

  if (blockIdx.x < 512) {
    // ---- KEY CONV1: CP=256, K=3, TCO=64, tile 64co x 64t ----
    const int blk = blockIdx.x;
    const int b = blk >> 5, co0 = ((blk >> 2) & 7) * 64, t0 = (blk & 3) * 64;
    const int wy = wid >> 1, wx = wid & 1;
    short* as = smem + 2640;  // [192][40]

    floatx4 acc[2][2];
    #pragma unroll
    for (int i = 0; i < 2; ++i)
      #pragma unroll
      for (int j = 0; j < 2; ++j) acc[i][j] = (floatx4){0.f, 0.f, 0.f, 0.f};

    for (int c0 = 0; c0 < 8; ++c0) {
      __syncthreads();
      for (int i = tid; i < 66 * 4; i += 256) {
        int row = i >> 2, c8 = (i & 3) * 8;
        int t = t0 + row - 1;
        int4 v = {0, 0, 0, 0};
        if (t >= 0 && t < 200)
          v = *(const int4*)&kT0[((size_t)b * 200 + t) * 256 + c0 * 32 + c8];
        *(int4*)&xs[row * 40 + c8] = v;
      }
      for (int i = tid; i < 192 * 4; i += 256) {
        int row = i >> 2, c8 = (i & 3) * 8;
        int dk = row >> 6, co = row & 63;
        *(int4*)&as[row * 40 + c8] =
            *(const int4*)&w1[((size_t)(dk * 512 + co0 + co)) * 256 + c0 * 32 + c8];
      }
      __syncthreads();
      #pragma unroll
      for (int dk = 0; dk < 3; ++dk) {
        short8 fa0 = *(const short8*)&as[(dk * 64 + wy * 32 + m) * 40 + q * 8];
        short8 fa1 = *(const short8*)&as[(dk * 64 + wy * 32 + 16 + m) * 40 + q * 8];
        #pragma unroll
        for (int j = 0; j < 2; ++j) {
          short8 fb = *(const short8*)&xs[(wx * 32 + j * 16 + m + dk) * 40 + q * 8];
          acc[0][j] = __builtin_amdgcn_mfma_f32_16x16x32_bf16(fa0, fb, acc[0][j], 0, 0, 0);
          acc[1][j] = __builtin_amdgcn_mfma_f32_16x16x32_bf16(fa1, fb, acc[1][j], 0, 0, 0);
        }
      }
    }
    #pragma unroll
    for (int i = 0; i < 2; ++i) {
      #pragma unroll
      for (int j = 0; j < 2; ++j) {
        #pragma unroll
        for (int r = 0; r < 4; ++r) {
          int co = co0 + wy * 32 + i * 16 + q * 4 + r;
          int t  = t0 + wx * 32 + j * 16 + m;
          if (t < 200) {
            float v = fmaxf(acc[i][j][r] + kb1[co], 0.f);
            kT1[((size_t)b * 200 + t) * 512 + co] = f2bf(v);
          }
        }
      }
    }
  } else {
    // ---- QUERY CHAIN (r3-verified) ----
    const int qbid = blockIdx.x - 512;
    const int b = qbid / 13, t0 = (qbid % 13) * 64;
    short* y1c = smem + 2640;    // [6][64][40]
    short* y2c = smem + 18000;   // [3][64][40]

    floatx4 accq[3][4];
    #pragma unroll
    for (int f = 0; f < 3; ++f)
      #pragma unroll
      for (int tf = 0; tf < 4; ++tf) accq[f][tf] = (floatx4){0.f, 0.f, 0.f, 0.f};

    for (int c0 = 0; c0 < 3; ++c0) {
      __syncthreads();
      for (int i = tid; i < 66 * 4; i += 256) {
        int row = i >> 2, c8 = (i & 3) * 8;
        int t = t0 + row - 1;
        int4 v = {0, 0, 0, 0};
        if (t >= 0 && t < 800)
          v = *(const int4*)&qT0[((size_t)b * 800 + t) * 96 + c0 * 32 + c8];
        *(int4*)&xs[row * 40 + c8] = v;
      }
      __syncthreads();
      #pragma unroll
      for (int dk = 0; dk < 3; ++dk) {
        short8 fa[3];
        #pragma unroll
        for (int f = 0; f < 3; ++f)
          fa[f] = *(const short8*)&w3[((size_t)(dk * 192 + wid * 48 + f * 16 + m)) * 96
                                      + c0 * 32 + q * 8];
        #pragma unroll
        for (int tf = 0; tf < 4; ++tf) {
          short8 fb = *(const short8*)&xs[(tf * 16 + m + dk) * 40 + q * 8];
          #pragma unroll
          for (int f = 0; f < 3; ++f)
            accq[f][tf] = __builtin_amdgcn_mfma_f32_16x16x32_bf16(fa[f], fb, accq[f][tf], 0, 0, 0);
        }
      }
    }
    __syncthreads();
    #pragma unroll
    for (int f = 0; f < 3; ++f) {
      #pragma unroll
      for (int tf = 0; tf < 4; ++tf) {
        int co = wid * 48 + f * 16 + q * 4;
        int t  = tf * 16 + m;
        short4v o;
        #pragma unroll
        for (int r = 0; r < 4; ++r) {
          float bv = (co + r < 160) ? qb1[co + r] : 0.f;
          o[r] = f2bf(fmaxf(accq[f][tf][r] + bv, 0.f));
        }
        *(short4v*)&y1c[(co >> 5) * 2560 + t * 40 + (co & 31)] = o;
      }
    }
    __syncthreads();

    floatx4 acc2q[6];
    #pragma unroll
    for (int f = 0; f < 6; ++f) acc2q[f] = (floatx4){0.f, 0.f, 0.f, 0.f};
    #pragma unroll
    for (int c = 0; c < 6; ++c) {
      short8 fb = *(const short8*)&y1c[c * 2560 + (wid * 16 + m) * 40 + q * 8];
      #pragma unroll
      for (int f = 0; f < 6; ++f) {
        short8 fa = *(const short8*)&w4[((size_t)(f * 16 + m)) * 192 + c * 32 + q * 8];
        acc2q[f] = __builtin_amdgcn_mfma_f32_16x16x32_bf16(fa, fb, acc2q[f], 0, 0, 0);
      }
    }
    #pragma unroll
    for (int f = 0; f < 6; ++f) {
      int co = f * 16 + q * 4;
      int t  = wid * 16 + m;
      short4v o;
      #pragma unroll
      for (int r = 0; r < 4; ++r) {
        float bv = (co + r < 80) ? qb2[co + r] : 0.f;
        o[r] = f2bf(fmaxf(acc2q[f][r] + bv, 0.f));
      }
      *(short4v*)&y2c[(co >> 5) * 2560 + t * 40 + (co & 31)] = o;
    }
    __syncthreads();

    floatx4 acc3q[6];
    #pragma unroll
    for (int f = 0; f < 6; ++f) acc3q[f] = (floatx4){0.f, 0.f, 0.f, 0.f};
    #pragma unroll
    for (int c = 0; c < 3; ++c) {
      short8 fb = *(const short8*)&y2c[c * 2560 + (wid * 16 + m) * 40 + q * 8];
      #pragma unroll
      for (int f = 0; f < 6; ++f) {
        short8 fa = *(const short8*)&w5[((size_t)(f * 16 + m)) * 96 + c * 32 + q * 8];
        acc3q[f] = __builtin_amdgcn_mfma_f32_16x16x32_bf16(fa, fb, acc3q[f], 0, 0, 0);
      }
    }
    int t = t0 + wid * 16 + m;
    if (t < 800) {
      #pragma unroll
      for (int f = 0; f < 6; ++f) {
        int co = f * 16 + q * 4;
        short4v o;
        #pragma unroll
        for (int r = 0; r < 4; ++r) {
          float bv = (co + r < 80) ? qb3[co + r] : 0.f;
          o[r] = f2bf(acc3q[f][r] + bv);
        }
        *(short4v*)&qF[((size_t)b * 800 + t) * 96 + co] = o;
      }
    }
  }
}

// ===========================================================================
// kconv2: key 512->80 k1, fragments straight from L2. 64 blocks x 4 waves,
// each wave owns 16 t rows. D: col=m -> t, row=q*4+r -> co (r3-verified map).
// ===========================================================================
__global__ __launch_bounds__(256) void kconv2_kernel(
    const short* __restrict__ kT1, const short* __restrict__ w2,
    const float* __restrict__ kb2, short* __restrict__ kF)
{
  const int blk = blockIdx.x;
  const int b = blk >> 2, t0 = (blk & 3) * 64;
  const int tid = threadIdx.x, wid = tid >> 6, lane = tid & 63;
  const int q = lane >> 4, m = lane & 15;
  const int t = t0 + wid * 16 + m;
  const bool tv = (t < 200);

  floatx4 acc[6];
  #pragma unroll
  for (int f = 0; f < 6; ++f) acc[f] = (floatx4){0.f, 0.f, 0.f, 0.f};

  #pragma unroll
  for (int c = 0; c < 16; ++c) {
    short8 fb;
    if (tv) fb = *(const short8*)&kT1[((size_t)b * 200 + t) * 512 + c * 32 + q * 8];
    else    fb = (short8){0,0,0,0,0,0,0,0};
    #pragma unroll
    for (int f = 0; f < 6; ++f) {
      short8 fa = *(const short8*)&w2[((size_t)(f * 16 + m)) * 512 + c * 32 + q * 8];
      acc[f] = __builtin_amdgcn_mfma_f32_16x16x32_bf16(fa, fb, acc[f], 0, 0, 0);
    }
  }
  if (tv) {
    #pragma unroll
    for (int f = 0; f < 6; ++f) {
      int co = f * 16 + q * 4;
      short4v o;
      #pragma unroll
      for (int r = 0; r < 4; ++r) {
        float bv = (co + r < 80) ? kb2[co + r] : 0.f;
        o[r] = f2bf(acc[f][r] + bv);
      }
      *(short4v*)&kF[((size_t)b * 200 + t) * 96 + co] = o;
    }
  }
}

// ===========================================================================
// Attention (verified r2/r3): S = q.k^T (K=96 zero-padded), q2 cancels,
// in-register log_softmax over 16-lane groups, + log(prior+1e-8).
// ===========================================================================
__global__ __launch_bounds__(256) void attn_mfma(
    const short* __restrict__ qT, const short* __restrict__ kT,
    const float* __restrict__ prior, float* __restrict__ out)
{
  const int b = blockIdx.y, t1_0 = blockIdx.x * 64;
  const int tid = threadIdx.x, wid = tid >> 6, lane = tid & 63;
  const int q = lane >> 4, m = lane & 15;

  __shared__ __align__(16) short aq[64 * 104];
  __shared__ __align__(16) short bk[208 * 40];
  __shared__ float k2s[208];

  floatx4 acc[13];
  #pragma unroll
  for (int f = 0; f < 13; ++f) acc[f] = (floatx4){0.f, 0.f, 0.f, 0.f};

  for (int i = tid; i < 64 * 12; i += 256) {
    int row = i / 12, g = i - (i / 12) * 12;
    int4 v = {0, 0, 0, 0};
    if (t1_0 + row < 800)
      v = *(const int4*)&qT[((size_t)b * 800 + t1_0 + row) * 96 + g * 8];
    *(int4*)&aq[row * 104 + g * 8] = v;
  }

  float k2acc = 0.f;
  for (int c = 0; c < 3; ++c) {
    __syncthreads();
    for (int i = tid; i < 208 * 4; i += 256) {
      int row = i >> 2, g = i & 3;
      int4 v = {0, 0, 0, 0};
      if (row < 200)
        v = *(const int4*)&kT[((size_t)b * 200 + row) * 96 + c * 32 + g * 8];
      *(int4*)&bk[row * 40 + g * 8] = v;
    }
    __syncthreads();
    if (tid < 208) {
      #pragma unroll
      for (int g = 0; g < 4; ++g) {
        short8 s = *(const short8*)&bk[tid * 40 + g * 8];
        #pragma unroll
        for (int j = 0; j < 8; ++j) {
          union { unsigned u; float f; } x; x.u = ((unsigned)(unsigned short)s[j]) << 16;
          k2acc = fmaf(x.f, x.f, k2acc);
        }
      }
    }
    short8 fa = *(const short8*)&aq[(wid * 16 + m) * 104 + c * 32 + q * 8];
    #pragma unroll
    for (int f = 0; f < 13; ++f) {
      short8 fb = *(const short8*)&bk[(f * 16 + m) * 40 + q * 8];
      acc[f] = __builtin_amdgcn_mfma_f32_16x16x32_bf16(fa, fb, acc[f], 0, 0, 0);
    }
  }
  if (tid < 208) k2s[tid] = k2acc;
  __syncthreads();

  float k2v[13];
  #pragma unroll
  for (int f = 0; f < 13; ++f) k2v[f] = k2s[f * 16 + m];

  float mx[4] = {-INFINITY, -INFINITY, -INFINITY, -INFINITY};
  #pragma unroll
  for (int f = 0; f < 13; ++f) {
    bool valid = (f * 16 + m) < 200;
    #pragma unroll
    for (int r = 0; r < 4; ++r) {
      float v = valid ? (0.001f * acc[f][r] - 0.0005f * k2v[f]) : -INFINITY;
      acc[f][r] = v;
      mx[r] = fmaxf(mx[r], v);
    }
  }
  #pragma unroll
  for (int msk = 1; msk < 16; msk <<= 1)
    #pragma unroll
    for (int r = 0; r < 4; ++r) mx[r] = fmaxf(mx[r], __shfl_xor(mx[r], msk));
  float sm[4] = {0.f, 0.f, 0.f, 0.f};
  #pragma unroll
  for (int f = 0; f < 13; ++f)
    #pragma unroll
    for (int r = 0; r < 4; ++r) sm[r] += __expf(acc[f][r] - mx[r]);
  #pragma unroll
  for (int msk = 1; msk < 16; msk <<= 1)
    #pragma unroll
    for (int r = 0; r < 4; ++r) sm[r] += __shfl_xor(sm[r], msk);
  float lse[4];
  #pragma unroll
  for (int r = 0; r < 4; ++r) lse[r] = mx[r] + __logf(sm[r]);

  #pragma unroll
  for (int f = 0; f < 13; ++f) {
    int col = f * 16 + m;
    if (col < 200) {
      #pragma unroll
      for (int r = 0; r < 4; ++r) {
        int t1 = t1_0 + wid * 16 + q * 4 + r;
        if (t1 < 800) {
          size_t o = ((size_t)b * 800 + t1) * 200 + col;
          out[o] = acc[f][r] - lse[r] + __logf(prior[o] + 1e-8f);
        }
      }
    }
  }
}

extern "C" void kernel_launch(void* const* d_in, const int* in_sizes, int n_in,
                              void* d_out, int out_size, void* d_ws, size_t ws_size,
                              hipStream_t stream) {
  const float* queries = (const float*)d_in[0];
  const float* keys    = (const float*)d_in[1];
  const float* prior   = (const float*)d_in[2];
  const float* kw1 = (const float*)d_in[3];
  const float* kb1 = (const float*)d_in[4];
  const float* kw2 = (const float*)d_in[5];
  const float* kb2 = (const float*)d_in[6];
  const float* qw1 = (const float*)d_in[7];
  const float* qb1 = (const float*)d_in[8];
  const float* qw2 = (const float*)d_in[9];
  const float* qb2 = (const float*)d_in[10];
  const float* qw3 = (const float*)d_in[11];
  const float* qb3 = (const float*)d_in[12];
  float* out = (float*)d_out;

  short* p = (short*)d_ws;
  short* kT0 = p;  p += (size_t)3200 * 256;
  short* qT0 = p;  p += (size_t)12800 * 96;
  short* w1  = p;  p += (size_t)3 * 512 * 256;
  short* w2  = p;  p += (size_t)96 * 512;
  short* w3  = p;  p += (size_t)3 * 192 * 96;
  short* w4  = p;  p += (size_t)96 * 192;
  short* w5  = p;  p += (size_t)96 * 96;
  short* kT1 = p;  p += (size_t)3200 * 512;
  short* kF  = p;  p += (size_t)3200 * 96;
  short* qF  = p;  p += (size_t)12800 * 96;

  prep_kernel<<<dim3(1649), 256, 0, stream>>>(keys, queries, kw1, kw2, qw1, qw2, qw3,
                                              kT0, qT0, w1, w2, w3, w4, w5);
  conv_k3_kernel<<<dim3(720), 256, 0, stream>>>(kT0, qT0, w1, w3, w4, w5,
                                                kb1, qb1, qb2, qb3, kT1, qF);
  kconv2_kernel<<<dim3(64), 256, 0, stream>>>(kT1, w2, kb2, kF);
  attn_mfma<<<dim3(13, 16), 256, 0, stream>>>(qF, kF, prior, out);
}